// Round 2
// baseline (4842.754 us; speedup 1.0000x reference)
//
#include <hip/hip_runtime.h>

#define N_ALL 4096
#define N_LAB 1024
#define DIMF 1024
#define EDGECAP 32768
#define ALPHA_ 0.99f
#define NIT_CH 80
#define EPS_D 2.220446049250313e-16

typedef short bf16x8 __attribute__((ext_vector_type(8)));
typedef float f32x4 __attribute__((ext_vector_type(4)));

struct __align__(8) Edge { unsigned j; float w; };

__device__ inline const float* xrow(const float* L, const float* U, int r) {
  return (r < N_LAB) ? (L + (size_t)r * DIMF) : (U + (size_t)(r - N_LAB) * DIMF);
}

__device__ inline void load_lds16(const void* g, void* l) {
  __builtin_amdgcn_global_load_lds(
      (const __attribute__((address_space(1))) unsigned int*)g,
      (__attribute__((address_space(3))) unsigned int*)l, 16, 0, 0);
}

__device__ inline unsigned short bf16rne(float f) {
  unsigned u = __float_as_uint(f);
  unsigned r = (u + 0x7fffu + ((u >> 16) & 1u)) >> 16;
  return (unsigned short)r;
}

// ------- prep: fp32 -> bf16 copy + fp32 & fp64 row norms — verbatim -------
__global__ __launch_bounds__(256) void prep_k(const float* __restrict__ L,
                                              const float* __restrict__ U,
                                              unsigned short* __restrict__ Xbf,
                                              float* __restrict__ sq,
                                              double* __restrict__ sqd) {
  const int row = blockIdx.x;
  const int tid = threadIdx.x;
  const float* src = xrow(L, U, row);
  float4 v = ((const float4*)src)[tid];
  ushort4 h;
  h.x = bf16rne(v.x); h.y = bf16rne(v.y); h.z = bf16rne(v.z); h.w = bf16rne(v.w);
  ((ushort4*)(Xbf + (size_t)row * DIMF))[tid] = h;
  float s = v.x * v.x + v.y * v.y + v.z * v.z + v.w * v.w;
  double sd = (double)v.x * v.x + (double)v.y * v.y +
              (double)v.z * v.z + (double)v.w * v.w;
#pragma unroll
  for (int d = 32; d >= 1; d >>= 1) {
    s += __shfl_xor(s, d);
    sd += __shfl_xor(sd, d);
  }
  __shared__ float wsum[4];
  __shared__ double wsumd[4];
  if ((tid & 63) == 0) { wsum[tid >> 6] = s; wsumd[tid >> 6] = sd; }
  __syncthreads();
  if (tid == 0) {
    sq[row] = wsum[0] + wsum[1] + wsum[2] + wsum[3];
    sqd[row] = wsumd[0] + wsumd[1] + wsumd[2] + wsumd[3];
  }
}

// ------- MFMA bf16 gram -> fp16 RANKING PROXY — verbatim -------
__global__ __launch_bounds__(256) void gemm_w(const unsigned short* __restrict__ Xbf,
                                              const float* __restrict__ sq,
                                              _Float16* __restrict__ Wh) {
  __shared__ unsigned short At[128 * 32];
  __shared__ unsigned short Bt[128 * 32];
  const int tid = threadIdx.x;
  const int wave = tid >> 6, lane = tid & 63;
  const int brow = blockIdx.y * 128, bcol = blockIdx.x * 128;
  const int q = lane >> 4, rl = lane & 15;
  const int wr = (wave >> 1) * 64, wc = (wave & 1) * 64;

  f32x4 acc[4][4] = {};

  const int srow = tid >> 2;
  const int soff = (tid & 3) * 8;

  for (int k0 = 0; k0 < DIMF; k0 += 32) {
#pragma unroll
    for (int half = 0; half < 2; ++half) {
      const unsigned short* ga =
          Xbf + (size_t)(brow + half * 64 + srow) * DIMF + k0 + soff;
      load_lds16(ga, &At[(half * 64 + wave * 16) * 32]);
      const unsigned short* gb =
          Xbf + (size_t)(bcol + half * 64 + srow) * DIMF + k0 + soff;
      load_lds16(gb, &Bt[(half * 64 + wave * 16) * 32]);
    }
    __syncthreads();
    bf16x8 af[4], bf_[4];
#pragma unroll
    for (int t = 0; t < 4; ++t) {
      af[t] = *(const bf16x8*)&At[(wr + t * 16 + rl) * 32 + q * 8];
      bf_[t] = *(const bf16x8*)&Bt[(wc + t * 16 + rl) * 32 + q * 8];
    }
#pragma unroll
    for (int i = 0; i < 4; ++i)
#pragma unroll
      for (int j = 0; j < 4; ++j)
        acc[i][j] = __builtin_amdgcn_mfma_f32_16x16x32_bf16(af[i], bf_[j], acc[i][j], 0, 0, 0);
    __syncthreads();
  }

#pragma unroll
  for (int i = 0; i < 4; ++i) {
#pragma unroll
    for (int j = 0; j < 4; ++j) {
#pragma unroll
      for (int reg = 0; reg < 4; ++reg) {
        int gr = brow + wr + i * 16 + q * 4 + reg;
        int gc = bcol + wc + j * 16 + rl;
        float g = acc[i][j][reg];
        float dist = sq[gr] + sq[gc] - 2.0f * g;   // unnormalized
        float val = fmaxf(2600.0f - dist, 0.25f);
        if (gr == gc) val = 0.0f;
        Wh[(size_t)gr * N_ALL + gc] = (_Float16)val;
      }
    }
  }
}

// ------- top-8 candidates per row (fp16 proxy), single scan — verbatim -------
__global__ __launch_bounds__(256) void top8_k(const _Float16* __restrict__ Wh,
                                              unsigned* __restrict__ t8i) {
  const int wave = threadIdx.x >> 6, lane = threadIdx.x & 63;
  const int row = blockIdx.x * 4 + wave;
  const _Float16* Wr = Wh + (size_t)row * N_ALL;
  float bv[8]; unsigned bj[8];
#pragma unroll
  for (int t = 0; t < 8; ++t) { bv[t] = -1.0f; bj[t] = 0xFFFFFFFFu; }
  float minv = -1.0f; int mins = 0;
  for (int s = 0; s < 64; ++s) {
    int j = s * 64 + lane;
    float v = (float)Wr[j];
    if (v > minv) {
#pragma unroll
      for (int t = 0; t < 8; ++t) if (t == mins) { bv[t] = v; bj[t] = (unsigned)j; }
      minv = bv[0]; mins = 0;
#pragma unroll
      for (int t = 1; t < 8; ++t) if (bv[t] < minv) { minv = bv[t]; mins = t; }
    }
  }
  for (int pick = 0; pick < 8; ++pick) {
    unsigned long long best = 0;
#pragma unroll
    for (int t = 0; t < 8; ++t) {
      bool valid = (bv[t] >= 0.0f);
      unsigned long long key =
          ((unsigned long long)__float_as_uint(bv[t]) << 32) |
          (unsigned long long)(0xFFFFFFFFu - bj[t]);
      if (valid && key > best) best = key;
    }
#pragma unroll
    for (int d = 32; d >= 1; d >>= 1) {
      unsigned long long o = __shfl_xor(best, d);
      if (o > best) best = o;
    }
    unsigned wj = 0xFFFFFFFFu - (unsigned)(best & 0xFFFFFFFFull);
    if (lane == 0) t8i[row * 8 + pick] = wj;
#pragma unroll
    for (int t = 0; t < 8; ++t) if (bj[t] == wj) bv[t] = -1.0f;
  }
}

// ------- fp64-exact rerank -> exact top-4 — verbatim -------
__global__ __launch_bounds__(256) void rerank_k(const float* __restrict__ L,
                                                const float* __restrict__ U,
                                                const double* __restrict__ sqd,
                                                const unsigned* __restrict__ t8i,
                                                unsigned* __restrict__ t4i) {
  const int wave = threadIdx.x >> 6, lane = threadIdx.x & 63;
  const int row = blockIdx.x * 4 + wave;
  const float* xi = xrow(L, U, row);
  float xr[16];
#pragma unroll
  for (int t = 0; t < 16; ++t) xr[t] = xi[t * 64 + lane];
  unsigned cj[8];
  double cw[8];
#pragma unroll
  for (int c = 0; c < 8; ++c) cj[c] = t8i[row * 8 + c];
  for (int c = 0; c < 8; ++c) {
    const float* xj = xrow(L, U, (int)cj[c]);
    double s = 0.0;
#pragma unroll
    for (int t = 0; t < 16; ++t) s += (double)xr[t] * xj[t * 64 + lane];
#pragma unroll
    for (int d = 32; d >= 1; d >>= 1) s += __shfl_xor(s, d);
    double dist = (sqd[row] + sqd[cj[c]] - 2.0 * s) * (1.0 / 1024.0);
    cw[c] = exp(-0.5 * dist);
  }
  if (lane == 0) {
#pragma unroll
    for (int pick = 0; pick < 4; ++pick) {
      int ms = -1;
      double mv = -1.0;
      unsigned mj = 0xFFFFFFFFu;
#pragma unroll
      for (int c = 0; c < 8; ++c) {
        bool better = (cw[c] > mv) || (cw[c] == mv && cj[c] < mj);
        if (cw[c] >= 0.0 && better) { mv = cw[c]; mj = cj[c]; ms = c; }
      }
      t4i[row * 4 + pick] = mj;
      cw[ms] = -2.0;
    }
  }
}

// ------- count kept edges per row — verbatim -------
__global__ __launch_bounds__(256) void cnt4_k(const unsigned* __restrict__ t4i,
                                              unsigned* __restrict__ nn) {
  const int wave = threadIdx.x >> 6, lane = threadIdx.x & 63;
  const int i = blockIdx.x * 4 + wave;
  const uint4 mine = ((const uint4*)t4i)[i];
  unsigned base = 0;
  for (int j0 = 0; j0 < N_ALL; j0 += 64) {
    int j = j0 + lane;
    uint4 tj = ((const uint4*)t4i)[j];
    bool keep = (mine.x == (unsigned)j) | (mine.y == (unsigned)j) |
                (mine.z == (unsigned)j) | (mine.w == (unsigned)j) |
                (tj.x == (unsigned)i) | (tj.y == (unsigned)i) |
                (tj.z == (unsigned)i) | (tj.w == (unsigned)i);
    keep = keep && (j != i);
    base += (unsigned)__popcll(__ballot(keep));
  }
  if (lane == 0) nn[i] = base;
}

// ------- exclusive scan of nn -> CSR rowPtr + label-layout probe — verbatim -------
__global__ __launch_bounds__(64) void scanP_k(const unsigned* __restrict__ nn,
                                              unsigned* __restrict__ rowPtr,
                                              const int* __restrict__ lab,
                                              int* __restrict__ labflag) {
  const int lane = threadIdx.x;
  const long long* l64 = (const long long*)lab;
  int bad = 0;
#pragma unroll
  for (int k = 0; k < 8; ++k) {
    long long v = l64[k * 64 + lane];
    if (v != 0 && v != 1) bad = 1;
  }
  unsigned long long bm = __ballot(bad);
  if (lane == 0) labflag[0] = (bm != 0ull) ? 0 : 1;
  unsigned running = 0;
  for (int j0 = 0; j0 < N_ALL; j0 += 64) {
    int v = (int)nn[j0 + lane];
    int incl = v;
#pragma unroll
    for (int d = 1; d < 64; d <<= 1) {
      int t = __shfl_up(incl, d);
      if (lane >= d) incl += t;
    }
    rowPtr[j0 + lane] = running + (unsigned)(incl - v);
    running += (unsigned)__shfl(incl, 63);
  }
  if (lane == 0) rowPtr[N_ALL] = running;
}

// ------- CSR index fill — verbatim -------
__global__ __launch_bounds__(256) void csrfill_k(const unsigned* __restrict__ t4i,
                                                 const unsigned* __restrict__ rowPtr,
                                                 Edge* __restrict__ edges,
                                                 unsigned* __restrict__ eRow) {
  const int wave = threadIdx.x >> 6, lane = threadIdx.x & 63;
  const int i = blockIdx.x * 4 + wave;
  const uint4 mine = ((const uint4*)t4i)[i];
  unsigned base = rowPtr[i];
  for (int j0 = 0; j0 < N_ALL; j0 += 64) {
    int j = j0 + lane;
    uint4 tj = ((const uint4*)t4i)[j];
    bool keep = (mine.x == (unsigned)j) | (mine.y == (unsigned)j) |
                (mine.z == (unsigned)j) | (mine.w == (unsigned)j) |
                (tj.x == (unsigned)i) | (tj.y == (unsigned)i) |
                (tj.z == (unsigned)i) | (tj.w == (unsigned)i);
    keep = keep && (j != i);
    unsigned long long m = __ballot(keep);
    if (keep) {
      unsigned pos = base + (unsigned)__popcll(m & ((1ull << lane) - 1ull));
      edges[pos].j = (unsigned)j;
      edges[pos].w = 0.0f;
      eRow[pos] = (unsigned)i;
    }
    base += (unsigned)__popcll(m);
  }
}

// ------- exact edge values — verbatim -------
__global__ __launch_bounds__(256) void edgeval_k(const float* __restrict__ L,
                                                 const float* __restrict__ U,
                                                 const double* __restrict__ sqd,
                                                 const unsigned* __restrict__ rowPtr,
                                                 const unsigned* __restrict__ eRow,
                                                 Edge* __restrict__ edges) {
  const int wave = threadIdx.x >> 6, lane = threadIdx.x & 63;
  const unsigned e = blockIdx.x * 4 + wave;
  if (e >= rowPtr[N_ALL]) return;
  const unsigned i = eRow[e];
  const unsigned j = edges[e].j;
  const float* xi = xrow(L, U, (int)i);
  const float* xj = xrow(L, U, (int)j);
  double s = 0.0;
#pragma unroll
  for (int t = 0; t < 16; ++t)
    s += (double)xi[t * 64 + lane] * xj[t * 64 + lane];
#pragma unroll
  for (int d = 32; d >= 1; d >>= 1) s += __shfl_xor(s, d);
  if (lane == 0) {
    double dist = (sqd[i] + sqd[j] - 2.0 * s) * (1.0 / 1024.0);
    edges[e].w = (float)exp(-0.5 * dist);
  }
}

// ------- degrees from exact edge values — verbatim -------
__global__ __launch_bounds__(256) void degE_k(const unsigned* __restrict__ rowPtr,
                                              const Edge* __restrict__ edges,
                                              float* __restrict__ Dis) {
  const int wave = threadIdx.x >> 6, lane = threadIdx.x & 63;
  const int i = blockIdx.x * 4 + wave;
  const unsigned b0 = rowPtr[i], b1 = rowPtr[i + 1];
  double ds = 0.0;
  for (unsigned e = b0 + lane; e < b1; e += 64) ds += (double)edges[e].w;
#pragma unroll
  for (int d = 32; d >= 1; d >>= 1) ds += __shfl_xor(ds, d);
  if (lane == 0) Dis[i] = (float)sqrt(1.0 / (ds + EPS_D));
}

// ------- scale edges — verbatim -------
__global__ __launch_bounds__(256) void scaleE_k(const unsigned* __restrict__ rowPtr,
                                                const unsigned* __restrict__ eRow,
                                                const float* __restrict__ Dis,
                                                Edge* __restrict__ edges) {
  const unsigned e = blockIdx.x * 256 + threadIdx.x;
  if (e >= rowPtr[N_ALL]) return;
  Edge ed = edges[e];
  edges[e].w = ed.w * Dis[eRow[e]] * Dis[ed.j];
}

// ------- persistent single-workgroup Chebyshev solver, v2 -------
// v1 post-mortem: caching edges in VGPRs (72 regs of state) spilled to
// scratch (VGPR_Count=64 < ~88 live) -> 4850 us, 85% stall on scratch
// reloads. v2 keeps NO per-edge register state: edges stream from global
// (256 KB, L2-resident) every iteration via contiguous CSR spans; per-thread
// state is just x/r/d for its 4 rows + CSR bounds (~40 VGPRs, cannot spill).
// Thread t owns rows {t, t+1024, t+2048, t+3072} (interleaved) so the
// dsh[row] float2 writes are the natural contiguous stride (conflict-free);
// d for own rows lives in registers (dreg), dsh is only for neighbor gathers.
// Two __syncthreads per iteration replace a kernel-launch boundary.
__global__ __launch_bounds__(1024, 4) void chebsolve_k(
    const Edge* __restrict__ edges,
    const unsigned* __restrict__ rowPtr,
    const int* __restrict__ lab,
    const int* __restrict__ labflag,
    float2* __restrict__ out) {
  __shared__ float2 dsh[N_ALL];
  const int t = threadIdx.x;

  float2 xv[4], rv[4], dreg[4];
  unsigned rp0[4], rp1[4];

  const int isI64 = labflag[0];

#pragma unroll
  for (int q = 0; q < 4; ++q) {
    const int row = t + q * 1024;
    float2 b = make_float2(0.0f, 0.0f);
    if (q == 0) {  // rows < N_LAB are exactly q==0
      int c = isI64 ? lab[2 * row] : lab[row];
      b.x = (c == 0) ? 1.0f : 0.0f;
      b.y = (c == 1) ? 1.0f : 0.0f;
    }
    xv[q] = make_float2(0.0f, 0.0f);
    rv[q] = b;
    dreg[q] = b;
    dsh[row] = b;
    rp0[q] = rowPtr[row];
    rp1[q] = rowPtr[row + 1];
  }
  __syncthreads();

  const double theta = 1.0, delta = 0.992;
  const double sigma1 = theta / delta;
  double rho = delta / theta;

  for (int it = 0; it < NIT_CH; ++it) {
    const double rho_new = 1.0 / (2.0 * sigma1 - rho);
    const float c1 = (float)(rho_new * rho);
    const float c2 = (float)(2.0 * rho_new / delta);
    rho = rho_new;
    const bool last = (it == NIT_CH - 1);

    float ax[4], ay[4];
#pragma unroll
    for (int q = 0; q < 4; ++q) {
      float sx = 0.0f, sy = 0.0f;
      for (unsigned e = rp0[q]; e < rp1[q]; ++e) {
        Edge ed = edges[e];              // L2-resident stream
        const float2 dj = dsh[ed.j];     // random LDS gather
        sx += ed.w * dj.x;
        sy += ed.w * dj.y;
      }
      ax[q] = sx;
      ay[q] = sy;
    }
    __syncthreads();                     // all gathers done before d update
#pragma unroll
    for (int q = 0; q < 4; ++q) {
      const float2 di = dreg[q];
      xv[q].x += di.x;
      xv[q].y += di.y;
      rv[q].x += ALPHA_ * ax[q] - di.x;
      rv[q].y += ALPHA_ * ay[q] - di.y;
      if (!last) {
        float2 dn;
        dn.x = c1 * di.x + c2 * rv[q].x;
        dn.y = c1 * di.y + c2 * rv[q].y;
        dreg[q] = dn;
        dsh[t + q * 1024] = dn;
      }
    }
    __syncthreads();                     // d visible before next gather
  }

#pragma unroll
  for (int q = 1; q < 4; ++q) {
    const int row = t + q * 1024;
    out[row - N_LAB] = xv[q];
  }
}

// ---------------- launch ----------------
extern "C" void kernel_launch(void* const* d_in, const int* in_sizes, int n_in,
                              void* d_out, int out_size, void* d_ws, size_t ws_size,
                              hipStream_t stream) {
  int iL = 0, iT = 1, iU = 2;
  for (int i = 0; i < n_in; ++i) {
    if (in_sizes[i] == N_LAB * DIMF) iL = i;
    else if (in_sizes[i] == (N_ALL - N_LAB) * DIMF) iU = i;
    else iT = i;
  }
  const float* L = (const float*)d_in[iL];
  const int* lab = (const int*)d_in[iT];
  const float* U = (const float*)d_in[iU];
  float2* out = (float2*)d_out;

  char* w = (char*)d_ws;
  size_t off = 0;
  auto alloc = [&](size_t bytes) {
    void* p = (void*)(w + off);
    off += (bytes + 255) & ~(size_t)255;
    return p;
  };
  _Float16* Wh = (_Float16*)alloc((size_t)N_ALL * N_ALL * 2);     // 32 MB proxy
  unsigned short* Xbf = (unsigned short*)alloc((size_t)N_ALL * DIMF * 2);  // 8 MB
  float* sq = (float*)alloc(N_ALL * 4);
  double* sqd = (double*)alloc(N_ALL * 8);
  unsigned* t8i = (unsigned*)alloc(N_ALL * 8 * 4);
  unsigned* t4i = (unsigned*)alloc(N_ALL * 4 * 4);
  float* Dis = (float*)alloc(N_ALL * 4);
  unsigned* nn = (unsigned*)alloc(N_ALL * 4);
  unsigned* rowPtr = (unsigned*)alloc((N_ALL + 1) * 4);
  int* labflag = (int*)alloc(256);
  Edge* edges = (Edge*)alloc((size_t)EDGECAP * sizeof(Edge));     // 256 KB
  unsigned* eRow = (unsigned*)alloc((size_t)EDGECAP * 4);         // 128 KB
  if (off > ws_size) return;

  prep_k<<<N_ALL, 256, 0, stream>>>(L, U, Xbf, sq, sqd);
  gemm_w<<<dim3(32, 32), 256, 0, stream>>>(Xbf, sq, Wh);
  top8_k<<<N_ALL / 4, 256, 0, stream>>>(Wh, t8i);
  rerank_k<<<N_ALL / 4, 256, 0, stream>>>(L, U, sqd, t8i, t4i);
  cnt4_k<<<N_ALL / 4, 256, 0, stream>>>(t4i, nn);
  scanP_k<<<1, 64, 0, stream>>>(nn, rowPtr, lab, labflag);
  csrfill_k<<<N_ALL / 4, 256, 0, stream>>>(t4i, rowPtr, edges, eRow);
  edgeval_k<<<EDGECAP / 4, 256, 0, stream>>>(L, U, sqd, rowPtr, eRow, edges);
  degE_k<<<N_ALL / 4, 256, 0, stream>>>(rowPtr, edges, Dis);
  scaleE_k<<<EDGECAP / 256, 256, 0, stream>>>(rowPtr, eRow, Dis, edges);
  chebsolve_k<<<1, 1024, 0, stream>>>(edges, rowPtr, lab, labflag, out);
}

// Round 3
// 1471.705 us; speedup vs baseline: 3.2906x; 3.2906x over previous
//
#include <hip/hip_runtime.h>

#define N_ALL 4096
#define N_LAB 1024
#define DIMF 1024
#define EDGECAP 32768
#define ALPHA_ 0.99f
#define NIT_CH 80
#define EPS_D 2.220446049250313e-16

typedef short bf16x8 __attribute__((ext_vector_type(8)));
typedef float f32x4 __attribute__((ext_vector_type(4)));

struct __align__(8) Edge { unsigned j; float w; };

__device__ inline const float* xrow(const float* L, const float* U, int r) {
  return (r < N_LAB) ? (L + (size_t)r * DIMF) : (U + (size_t)(r - N_LAB) * DIMF);
}

__device__ inline void load_lds16(const void* g, void* l) {
  __builtin_amdgcn_global_load_lds(
      (const __attribute__((address_space(1))) unsigned int*)g,
      (__attribute__((address_space(3))) unsigned int*)l, 16, 0, 0);
}

__device__ inline unsigned short bf16rne(float f) {
  unsigned u = __float_as_uint(f);
  unsigned r = (u + 0x7fffu + ((u >> 16) & 1u)) >> 16;
  return (unsigned short)r;
}

// ------- prep: fp32 -> bf16 copy + fp32 & fp64 row norms — verbatim -------
__global__ __launch_bounds__(256) void prep_k(const float* __restrict__ L,
                                              const float* __restrict__ U,
                                              unsigned short* __restrict__ Xbf,
                                              float* __restrict__ sq,
                                              double* __restrict__ sqd) {
  const int row = blockIdx.x;
  const int tid = threadIdx.x;
  const float* src = xrow(L, U, row);
  float4 v = ((const float4*)src)[tid];
  ushort4 h;
  h.x = bf16rne(v.x); h.y = bf16rne(v.y); h.z = bf16rne(v.z); h.w = bf16rne(v.w);
  ((ushort4*)(Xbf + (size_t)row * DIMF))[tid] = h;
  float s = v.x * v.x + v.y * v.y + v.z * v.z + v.w * v.w;
  double sd = (double)v.x * v.x + (double)v.y * v.y +
              (double)v.z * v.z + (double)v.w * v.w;
#pragma unroll
  for (int d = 32; d >= 1; d >>= 1) {
    s += __shfl_xor(s, d);
    sd += __shfl_xor(sd, d);
  }
  __shared__ float wsum[4];
  __shared__ double wsumd[4];
  if ((tid & 63) == 0) { wsum[tid >> 6] = s; wsumd[tid >> 6] = sd; }
  __syncthreads();
  if (tid == 0) {
    sq[row] = wsum[0] + wsum[1] + wsum[2] + wsum[3];
    sqd[row] = wsumd[0] + wsumd[1] + wsumd[2] + wsumd[3];
  }
}

// ------- MFMA bf16 gram -> fp16 RANKING PROXY — verbatim -------
__global__ __launch_bounds__(256) void gemm_w(const unsigned short* __restrict__ Xbf,
                                              const float* __restrict__ sq,
                                              _Float16* __restrict__ Wh) {
  __shared__ unsigned short At[128 * 32];
  __shared__ unsigned short Bt[128 * 32];
  const int tid = threadIdx.x;
  const int wave = tid >> 6, lane = tid & 63;
  const int brow = blockIdx.y * 128, bcol = blockIdx.x * 128;
  const int q = lane >> 4, rl = lane & 15;
  const int wr = (wave >> 1) * 64, wc = (wave & 1) * 64;

  f32x4 acc[4][4] = {};

  const int srow = tid >> 2;
  const int soff = (tid & 3) * 8;

  for (int k0 = 0; k0 < DIMF; k0 += 32) {
#pragma unroll
    for (int half = 0; half < 2; ++half) {
      const unsigned short* ga =
          Xbf + (size_t)(brow + half * 64 + srow) * DIMF + k0 + soff;
      load_lds16(ga, &At[(half * 64 + wave * 16) * 32]);
      const unsigned short* gb =
          Xbf + (size_t)(bcol + half * 64 + srow) * DIMF + k0 + soff;
      load_lds16(gb, &Bt[(half * 64 + wave * 16) * 32]);
    }
    __syncthreads();
    bf16x8 af[4], bf_[4];
#pragma unroll
    for (int t = 0; t < 4; ++t) {
      af[t] = *(const bf16x8*)&At[(wr + t * 16 + rl) * 32 + q * 8];
      bf_[t] = *(const bf16x8*)&Bt[(wc + t * 16 + rl) * 32 + q * 8];
    }
#pragma unroll
    for (int i = 0; i < 4; ++i)
#pragma unroll
      for (int j = 0; j < 4; ++j)
        acc[i][j] = __builtin_amdgcn_mfma_f32_16x16x32_bf16(af[i], bf_[j], acc[i][j], 0, 0, 0);
    __syncthreads();
  }

#pragma unroll
  for (int i = 0; i < 4; ++i) {
#pragma unroll
    for (int j = 0; j < 4; ++j) {
#pragma unroll
      for (int reg = 0; reg < 4; ++reg) {
        int gr = brow + wr + i * 16 + q * 4 + reg;
        int gc = bcol + wc + j * 16 + rl;
        float g = acc[i][j][reg];
        float dist = sq[gr] + sq[gc] - 2.0f * g;   // unnormalized
        float val = fmaxf(2600.0f - dist, 0.25f);
        if (gr == gc) val = 0.0f;
        Wh[(size_t)gr * N_ALL + gc] = (_Float16)val;
      }
    }
  }
}

// ------- top-8 candidates per row (fp16 proxy), single scan — verbatim -------
__global__ __launch_bounds__(256) void top8_k(const _Float16* __restrict__ Wh,
                                              unsigned* __restrict__ t8i) {
  const int wave = threadIdx.x >> 6, lane = threadIdx.x & 63;
  const int row = blockIdx.x * 4 + wave;
  const _Float16* Wr = Wh + (size_t)row * N_ALL;
  float bv[8]; unsigned bj[8];
#pragma unroll
  for (int t = 0; t < 8; ++t) { bv[t] = -1.0f; bj[t] = 0xFFFFFFFFu; }
  float minv = -1.0f; int mins = 0;
  for (int s = 0; s < 64; ++s) {
    int j = s * 64 + lane;
    float v = (float)Wr[j];
    if (v > minv) {
#pragma unroll
      for (int t = 0; t < 8; ++t) if (t == mins) { bv[t] = v; bj[t] = (unsigned)j; }
      minv = bv[0]; mins = 0;
#pragma unroll
      for (int t = 1; t < 8; ++t) if (bv[t] < minv) { minv = bv[t]; mins = t; }
    }
  }
  for (int pick = 0; pick < 8; ++pick) {
    unsigned long long best = 0;
#pragma unroll
    for (int t = 0; t < 8; ++t) {
      bool valid = (bv[t] >= 0.0f);
      unsigned long long key =
          ((unsigned long long)__float_as_uint(bv[t]) << 32) |
          (unsigned long long)(0xFFFFFFFFu - bj[t]);
      if (valid && key > best) best = key;
    }
#pragma unroll
    for (int d = 32; d >= 1; d >>= 1) {
      unsigned long long o = __shfl_xor(best, d);
      if (o > best) best = o;
    }
    unsigned wj = 0xFFFFFFFFu - (unsigned)(best & 0xFFFFFFFFull);
    if (lane == 0) t8i[row * 8 + pick] = wj;
#pragma unroll
    for (int t = 0; t < 8; ++t) if (bj[t] == wj) bv[t] = -1.0f;
  }
}

// ------- fp64-exact rerank -> exact top-4 — verbatim -------
__global__ __launch_bounds__(256) void rerank_k(const float* __restrict__ L,
                                                const float* __restrict__ U,
                                                const double* __restrict__ sqd,
                                                const unsigned* __restrict__ t8i,
                                                unsigned* __restrict__ t4i) {
  const int wave = threadIdx.x >> 6, lane = threadIdx.x & 63;
  const int row = blockIdx.x * 4 + wave;
  const float* xi = xrow(L, U, row);
  float xr[16];
#pragma unroll
  for (int t = 0; t < 16; ++t) xr[t] = xi[t * 64 + lane];
  unsigned cj[8];
  double cw[8];
#pragma unroll
  for (int c = 0; c < 8; ++c) cj[c] = t8i[row * 8 + c];
  for (int c = 0; c < 8; ++c) {
    const float* xj = xrow(L, U, (int)cj[c]);
    double s = 0.0;
#pragma unroll
    for (int t = 0; t < 16; ++t) s += (double)xr[t] * xj[t * 64 + lane];
#pragma unroll
    for (int d = 32; d >= 1; d >>= 1) s += __shfl_xor(s, d);
    double dist = (sqd[row] + sqd[cj[c]] - 2.0 * s) * (1.0 / 1024.0);
    cw[c] = exp(-0.5 * dist);
  }
  if (lane == 0) {
#pragma unroll
    for (int pick = 0; pick < 4; ++pick) {
      int ms = -1;
      double mv = -1.0;
      unsigned mj = 0xFFFFFFFFu;
#pragma unroll
      for (int c = 0; c < 8; ++c) {
        bool better = (cw[c] > mv) || (cw[c] == mv && cj[c] < mj);
        if (cw[c] >= 0.0 && better) { mv = cw[c]; mj = cj[c]; ms = c; }
      }
      t4i[row * 4 + pick] = mj;
      cw[ms] = -2.0;
    }
  }
}

// ------- count kept edges per row — verbatim -------
__global__ __launch_bounds__(256) void cnt4_k(const unsigned* __restrict__ t4i,
                                              unsigned* __restrict__ nn) {
  const int wave = threadIdx.x >> 6, lane = threadIdx.x & 63;
  const int i = blockIdx.x * 4 + wave;
  const uint4 mine = ((const uint4*)t4i)[i];
  unsigned base = 0;
  for (int j0 = 0; j0 < N_ALL; j0 += 64) {
    int j = j0 + lane;
    uint4 tj = ((const uint4*)t4i)[j];
    bool keep = (mine.x == (unsigned)j) | (mine.y == (unsigned)j) |
                (mine.z == (unsigned)j) | (mine.w == (unsigned)j) |
                (tj.x == (unsigned)i) | (tj.y == (unsigned)i) |
                (tj.z == (unsigned)i) | (tj.w == (unsigned)i);
    keep = keep && (j != i);
    base += (unsigned)__popcll(__ballot(keep));
  }
  if (lane == 0) nn[i] = base;
}

// ------- exclusive scan of nn -> CSR rowPtr + label-layout probe — verbatim -------
__global__ __launch_bounds__(64) void scanP_k(const unsigned* __restrict__ nn,
                                              unsigned* __restrict__ rowPtr,
                                              const int* __restrict__ lab,
                                              int* __restrict__ labflag) {
  const int lane = threadIdx.x;
  const long long* l64 = (const long long*)lab;
  int bad = 0;
#pragma unroll
  for (int k = 0; k < 8; ++k) {
    long long v = l64[k * 64 + lane];
    if (v != 0 && v != 1) bad = 1;
  }
  unsigned long long bm = __ballot(bad);
  if (lane == 0) labflag[0] = (bm != 0ull) ? 0 : 1;
  unsigned running = 0;
  for (int j0 = 0; j0 < N_ALL; j0 += 64) {
    int v = (int)nn[j0 + lane];
    int incl = v;
#pragma unroll
    for (int d = 1; d < 64; d <<= 1) {
      int t = __shfl_up(incl, d);
      if (lane >= d) incl += t;
    }
    rowPtr[j0 + lane] = running + (unsigned)(incl - v);
    running += (unsigned)__shfl(incl, 63);
  }
  if (lane == 0) rowPtr[N_ALL] = running;
}

// ------- CSR index fill — verbatim -------
__global__ __launch_bounds__(256) void csrfill_k(const unsigned* __restrict__ t4i,
                                                 const unsigned* __restrict__ rowPtr,
                                                 Edge* __restrict__ edges,
                                                 unsigned* __restrict__ eRow) {
  const int wave = threadIdx.x >> 6, lane = threadIdx.x & 63;
  const int i = blockIdx.x * 4 + wave;
  const uint4 mine = ((const uint4*)t4i)[i];
  unsigned base = rowPtr[i];
  for (int j0 = 0; j0 < N_ALL; j0 += 64) {
    int j = j0 + lane;
    uint4 tj = ((const uint4*)t4i)[j];
    bool keep = (mine.x == (unsigned)j) | (mine.y == (unsigned)j) |
                (mine.z == (unsigned)j) | (mine.w == (unsigned)j) |
                (tj.x == (unsigned)i) | (tj.y == (unsigned)i) |
                (tj.z == (unsigned)i) | (tj.w == (unsigned)i);
    keep = keep && (j != i);
    unsigned long long m = __ballot(keep);
    if (keep) {
      unsigned pos = base + (unsigned)__popcll(m & ((1ull << lane) - 1ull));
      edges[pos].j = (unsigned)j;
      edges[pos].w = 0.0f;
      eRow[pos] = (unsigned)i;
    }
    base += (unsigned)__popcll(m);
  }
}

// ------- exact edge values — verbatim -------
__global__ __launch_bounds__(256) void edgeval_k(const float* __restrict__ L,
                                                 const float* __restrict__ U,
                                                 const double* __restrict__ sqd,
                                                 const unsigned* __restrict__ rowPtr,
                                                 const unsigned* __restrict__ eRow,
                                                 Edge* __restrict__ edges) {
  const int wave = threadIdx.x >> 6, lane = threadIdx.x & 63;
  const unsigned e = blockIdx.x * 4 + wave;
  if (e >= rowPtr[N_ALL]) return;
  const unsigned i = eRow[e];
  const unsigned j = edges[e].j;
  const float* xi = xrow(L, U, (int)i);
  const float* xj = xrow(L, U, (int)j);
  double s = 0.0;
#pragma unroll
  for (int t = 0; t < 16; ++t)
    s += (double)xi[t * 64 + lane] * xj[t * 64 + lane];
#pragma unroll
  for (int d = 32; d >= 1; d >>= 1) s += __shfl_xor(s, d);
  if (lane == 0) {
    double dist = (sqd[i] + sqd[j] - 2.0 * s) * (1.0 / 1024.0);
    edges[e].w = (float)exp(-0.5 * dist);
  }
}

// ------- degrees from exact edge values — verbatim -------
__global__ __launch_bounds__(256) void degE_k(const unsigned* __restrict__ rowPtr,
                                              const Edge* __restrict__ edges,
                                              float* __restrict__ Dis) {
  const int wave = threadIdx.x >> 6, lane = threadIdx.x & 63;
  const int i = blockIdx.x * 4 + wave;
  const unsigned b0 = rowPtr[i], b1 = rowPtr[i + 1];
  double ds = 0.0;
  for (unsigned e = b0 + lane; e < b1; e += 64) ds += (double)edges[e].w;
#pragma unroll
  for (int d = 32; d >= 1; d >>= 1) ds += __shfl_xor(ds, d);
  if (lane == 0) Dis[i] = (float)sqrt(1.0 / (ds + EPS_D));
}

// ------- scale edges -> packed padded ELL-chunk stream -------
// epk[e] = {(row<<16) | flushbit(0x8000) | j, w_scaled}. row, j < 4096 (12
// bits each). flushbit marks "last edge of this row-segment within a
// 32-edge chunk" (row change, end of edges, or chunk boundary). Pad entries
// e in [E, EDGECAP): {0, 0.0f} -> contribute exact 0.0 to row 0.
__global__ __launch_bounds__(256) void scaleE_k(const unsigned* __restrict__ rowPtr,
                                                const unsigned* __restrict__ eRow,
                                                const float* __restrict__ Dis,
                                                const Edge* __restrict__ edges,
                                                uint2* __restrict__ epk) {
  const unsigned e = blockIdx.x * 256 + threadIdx.x;
  const unsigned E = rowPtr[N_ALL];
  if (e >= E) {
    if (e < EDGECAP) epk[e] = make_uint2(0u, 0u);
    return;
  }
  Edge ed = edges[e];
  const unsigned i = eRow[e];
  const float w = ed.w * Dis[i] * Dis[ed.j];
  const unsigned flush =
      ((e == E - 1) || (eRow[e + 1] != i) || ((e & 31u) == 31u)) ? 0x8000u : 0u;
  epk[e] = make_uint2((i << 16) | flush | ed.j, __float_as_uint(w));
}

// ------- persistent single-workgroup Chebyshev solver, v3 -------
// v2 post-mortem: v1 (reg-cached) and v2 (L2-streamed) both ~4850 us ->
// the shared cost is the PER-THREAD SERIAL edge loop over rows of unequal
// degree. High-dim kNN hubness gives some rows in-degree of hundreds; the
// owning thread walks ~360 dependent (L2 load -> LDS gather) chains
// (~400 cy each ~= the measured 60 us/iter) while 1023 threads wait at the
// barrier. v3: edge-parallel gather. Every thread processes EXACTLY 32
// contiguous packed edges (compile-time trip count -> unrolled, batched
// independent loads), accumulates row segments locally, and flushes via
// LDS atomicAdd into acc[4096]. Update phase stays row-owned: read acc,
// re-zero it, update x/r/d, write dsh. Worst-case per-thread work is now
// fixed at 32 edges regardless of hubs.
__global__ __launch_bounds__(1024, 4) void chebsolve_k(
    const uint2* __restrict__ epk,
    const int* __restrict__ lab,
    const int* __restrict__ labflag,
    float2* __restrict__ out) {
  __shared__ float2 dsh[N_ALL];   // 32 KB: d vector
  __shared__ float2 acc[N_ALL];   // 32 KB: per-row gather accumulator
  const int t = threadIdx.x;

  float2 xv[4], rv[4], dreg[4];
  const int isI64 = labflag[0];

#pragma unroll
  for (int q = 0; q < 4; ++q) {
    const int row = t + q * 1024;
    float2 b = make_float2(0.0f, 0.0f);
    if (q == 0) {  // rows < N_LAB are exactly q==0
      int c = isI64 ? lab[2 * row] : lab[row];
      b.x = (c == 0) ? 1.0f : 0.0f;
      b.y = (c == 1) ? 1.0f : 0.0f;
    }
    xv[q] = make_float2(0.0f, 0.0f);
    rv[q] = b;
    dreg[q] = b;
    dsh[row] = b;
    acc[row] = make_float2(0.0f, 0.0f);
  }
  __syncthreads();

  const double theta = 1.0, delta = 0.992;
  const double sigma1 = theta / delta;
  double rho = delta / theta;
  const unsigned base = (unsigned)t * 32u;

  for (int it = 0; it < NIT_CH; ++it) {
    const double rho_new = 1.0 / (2.0 * sigma1 - rho);
    const float c1 = (float)(rho_new * rho);
    const float c2 = (float)(2.0 * rho_new / delta);
    rho = rho_new;
    const bool last = (it == NIT_CH - 1);

    // ---- edge-parallel gather: 32 edges/thread, segmented atomic flush ----
    float sx = 0.0f, sy = 0.0f;
#pragma unroll
    for (int k = 0; k < 32; ++k) {
      const uint2 p = epk[base + k];
      const float w = __uint_as_float(p.y);
      const float2 dj = dsh[p.x & 0xFFFu];
      sx += w * dj.x;
      sy += w * dj.y;
      if (p.x & 0x8000u) {
        const unsigned row = p.x >> 16;
        atomicAdd(&acc[row].x, sx);
        atomicAdd(&acc[row].y, sy);
        sx = 0.0f;
        sy = 0.0f;
      }
    }
    __syncthreads();  // all atomics visible before row-owned update

    // ---- row-owned update; re-zero acc for the next iteration ----
#pragma unroll
    for (int q = 0; q < 4; ++q) {
      const int row = t + q * 1024;
      const float2 a = acc[row];
      acc[row] = make_float2(0.0f, 0.0f);
      const float2 di = dreg[q];
      xv[q].x += di.x;
      xv[q].y += di.y;
      rv[q].x += ALPHA_ * a.x - di.x;
      rv[q].y += ALPHA_ * a.y - di.y;
      if (!last) {
        float2 dn;
        dn.x = c1 * di.x + c2 * rv[q].x;
        dn.y = c1 * di.y + c2 * rv[q].y;
        dreg[q] = dn;
        dsh[row] = dn;
      }
    }
    __syncthreads();  // d + zeroed acc visible before next gather
  }

#pragma unroll
  for (int q = 1; q < 4; ++q) {
    const int row = t + q * 1024;
    out[row - N_LAB] = xv[q];
  }
}

// ---------------- launch ----------------
extern "C" void kernel_launch(void* const* d_in, const int* in_sizes, int n_in,
                              void* d_out, int out_size, void* d_ws, size_t ws_size,
                              hipStream_t stream) {
  int iL = 0, iT = 1, iU = 2;
  for (int i = 0; i < n_in; ++i) {
    if (in_sizes[i] == N_LAB * DIMF) iL = i;
    else if (in_sizes[i] == (N_ALL - N_LAB) * DIMF) iU = i;
    else iT = i;
  }
  const float* L = (const float*)d_in[iL];
  const int* lab = (const int*)d_in[iT];
  const float* U = (const float*)d_in[iU];
  float2* out = (float2*)d_out;

  char* w = (char*)d_ws;
  size_t off = 0;
  auto alloc = [&](size_t bytes) {
    void* p = (void*)(w + off);
    off += (bytes + 255) & ~(size_t)255;
    return p;
  };
  _Float16* Wh = (_Float16*)alloc((size_t)N_ALL * N_ALL * 2);     // 32 MB proxy
  unsigned short* Xbf = (unsigned short*)alloc((size_t)N_ALL * DIMF * 2);  // 8 MB
  float* sq = (float*)alloc(N_ALL * 4);
  double* sqd = (double*)alloc(N_ALL * 8);
  unsigned* t8i = (unsigned*)alloc(N_ALL * 8 * 4);
  unsigned* t4i = (unsigned*)alloc(N_ALL * 4 * 4);
  float* Dis = (float*)alloc(N_ALL * 4);
  unsigned* nn = (unsigned*)alloc(N_ALL * 4);
  unsigned* rowPtr = (unsigned*)alloc((N_ALL + 1) * 4);
  int* labflag = (int*)alloc(256);
  Edge* edges = (Edge*)alloc((size_t)EDGECAP * sizeof(Edge));     // 256 KB
  unsigned* eRow = (unsigned*)alloc((size_t)EDGECAP * 4);         // 128 KB
  uint2* epk = (uint2*)alloc((size_t)EDGECAP * 8);                // 256 KB packed
  if (off > ws_size) return;

  prep_k<<<N_ALL, 256, 0, stream>>>(L, U, Xbf, sq, sqd);
  gemm_w<<<dim3(32, 32), 256, 0, stream>>>(Xbf, sq, Wh);
  top8_k<<<N_ALL / 4, 256, 0, stream>>>(Wh, t8i);
  rerank_k<<<N_ALL / 4, 256, 0, stream>>>(L, U, sqd, t8i, t4i);
  cnt4_k<<<N_ALL / 4, 256, 0, stream>>>(t4i, nn);
  scanP_k<<<1, 64, 0, stream>>>(nn, rowPtr, lab, labflag);
  csrfill_k<<<N_ALL / 4, 256, 0, stream>>>(t4i, rowPtr, edges, eRow);
  edgeval_k<<<EDGECAP / 4, 256, 0, stream>>>(L, U, sqd, rowPtr, eRow, edges);
  degE_k<<<N_ALL / 4, 256, 0, stream>>>(rowPtr, edges, Dis);
  scaleE_k<<<EDGECAP / 256, 256, 0, stream>>>(rowPtr, eRow, Dis, edges, epk);
  chebsolve_k<<<1, 1024, 0, stream>>>(epk, lab, labflag, out);
}

// Round 4
// 1031.726 us; speedup vs baseline: 4.6938x; 1.4264x over previous
//
#include <hip/hip_runtime.h>

#define N_ALL 4096
#define N_LAB 1024
#define DIMF 1024
#define EDGECAP 32768
#define ALPHA_ 0.99f
#define NIT_CH 80
#define EPS_D 2.220446049250313e-16

typedef short bf16x8 __attribute__((ext_vector_type(8)));
typedef float f32x4 __attribute__((ext_vector_type(4)));

struct __align__(8) Edge { unsigned j; float w; };

__device__ inline const float* xrow(const float* L, const float* U, int r) {
  return (r < N_LAB) ? (L + (size_t)r * DIMF) : (U + (size_t)(r - N_LAB) * DIMF);
}

__device__ inline void load_lds16(const void* g, void* l) {
  __builtin_amdgcn_global_load_lds(
      (const __attribute__((address_space(1))) unsigned int*)g,
      (__attribute__((address_space(3))) unsigned int*)l, 16, 0, 0);
}

__device__ inline unsigned short bf16rne(float f) {
  unsigned u = __float_as_uint(f);
  unsigned r = (u + 0x7fffu + ((u >> 16) & 1u)) >> 16;
  return (unsigned short)r;
}

// ------- prep: fp32 -> bf16 copy + fp32 & fp64 row norms — verbatim -------
__global__ __launch_bounds__(256) void prep_k(const float* __restrict__ L,
                                              const float* __restrict__ U,
                                              unsigned short* __restrict__ Xbf,
                                              float* __restrict__ sq,
                                              double* __restrict__ sqd) {
  const int row = blockIdx.x;
  const int tid = threadIdx.x;
  const float* src = xrow(L, U, row);
  float4 v = ((const float4*)src)[tid];
  ushort4 h;
  h.x = bf16rne(v.x); h.y = bf16rne(v.y); h.z = bf16rne(v.z); h.w = bf16rne(v.w);
  ((ushort4*)(Xbf + (size_t)row * DIMF))[tid] = h;
  float s = v.x * v.x + v.y * v.y + v.z * v.z + v.w * v.w;
  double sd = (double)v.x * v.x + (double)v.y * v.y +
              (double)v.z * v.z + (double)v.w * v.w;
#pragma unroll
  for (int d = 32; d >= 1; d >>= 1) {
    s += __shfl_xor(s, d);
    sd += __shfl_xor(sd, d);
  }
  __shared__ float wsum[4];
  __shared__ double wsumd[4];
  if ((tid & 63) == 0) { wsum[tid >> 6] = s; wsumd[tid >> 6] = sd; }
  __syncthreads();
  if (tid == 0) {
    sq[row] = wsum[0] + wsum[1] + wsum[2] + wsum[3];
    sqd[row] = wsumd[0] + wsumd[1] + wsumd[2] + wsumd[3];
  }
}

// ------- MFMA bf16 gram -> fp16 RANKING PROXY — verbatim -------
__global__ __launch_bounds__(256) void gemm_w(const unsigned short* __restrict__ Xbf,
                                              const float* __restrict__ sq,
                                              _Float16* __restrict__ Wh) {
  __shared__ unsigned short At[128 * 32];
  __shared__ unsigned short Bt[128 * 32];
  const int tid = threadIdx.x;
  const int wave = tid >> 6, lane = tid & 63;
  const int brow = blockIdx.y * 128, bcol = blockIdx.x * 128;
  const int q = lane >> 4, rl = lane & 15;
  const int wr = (wave >> 1) * 64, wc = (wave & 1) * 64;

  f32x4 acc[4][4] = {};

  const int srow = tid >> 2;
  const int soff = (tid & 3) * 8;

  for (int k0 = 0; k0 < DIMF; k0 += 32) {
#pragma unroll
    for (int half = 0; half < 2; ++half) {
      const unsigned short* ga =
          Xbf + (size_t)(brow + half * 64 + srow) * DIMF + k0 + soff;
      load_lds16(ga, &At[(half * 64 + wave * 16) * 32]);
      const unsigned short* gb =
          Xbf + (size_t)(bcol + half * 64 + srow) * DIMF + k0 + soff;
      load_lds16(gb, &Bt[(half * 64 + wave * 16) * 32]);
    }
    __syncthreads();
    bf16x8 af[4], bf_[4];
#pragma unroll
    for (int t = 0; t < 4; ++t) {
      af[t] = *(const bf16x8*)&At[(wr + t * 16 + rl) * 32 + q * 8];
      bf_[t] = *(const bf16x8*)&Bt[(wc + t * 16 + rl) * 32 + q * 8];
    }
#pragma unroll
    for (int i = 0; i < 4; ++i)
#pragma unroll
      for (int j = 0; j < 4; ++j)
        acc[i][j] = __builtin_amdgcn_mfma_f32_16x16x32_bf16(af[i], bf_[j], acc[i][j], 0, 0, 0);
    __syncthreads();
  }

#pragma unroll
  for (int i = 0; i < 4; ++i) {
#pragma unroll
    for (int j = 0; j < 4; ++j) {
#pragma unroll
      for (int reg = 0; reg < 4; ++reg) {
        int gr = brow + wr + i * 16 + q * 4 + reg;
        int gc = bcol + wc + j * 16 + rl;
        float g = acc[i][j][reg];
        float dist = sq[gr] + sq[gc] - 2.0f * g;   // unnormalized
        float val = fmaxf(2600.0f - dist, 0.25f);
        if (gr == gc) val = 0.0f;
        Wh[(size_t)gr * N_ALL + gc] = (_Float16)val;
      }
    }
  }
}

// ------- top-8 candidates per row (fp16 proxy), single scan — verbatim -------
__global__ __launch_bounds__(256) void top8_k(const _Float16* __restrict__ Wh,
                                              unsigned* __restrict__ t8i) {
  const int wave = threadIdx.x >> 6, lane = threadIdx.x & 63;
  const int row = blockIdx.x * 4 + wave;
  const _Float16* Wr = Wh + (size_t)row * N_ALL;
  float bv[8]; unsigned bj[8];
#pragma unroll
  for (int t = 0; t < 8; ++t) { bv[t] = -1.0f; bj[t] = 0xFFFFFFFFu; }
  float minv = -1.0f; int mins = 0;
  for (int s = 0; s < 64; ++s) {
    int j = s * 64 + lane;
    float v = (float)Wr[j];
    if (v > minv) {
#pragma unroll
      for (int t = 0; t < 8; ++t) if (t == mins) { bv[t] = v; bj[t] = (unsigned)j; }
      minv = bv[0]; mins = 0;
#pragma unroll
      for (int t = 1; t < 8; ++t) if (bv[t] < minv) { minv = bv[t]; mins = t; }
    }
  }
  for (int pick = 0; pick < 8; ++pick) {
    unsigned long long best = 0;
#pragma unroll
    for (int t = 0; t < 8; ++t) {
      bool valid = (bv[t] >= 0.0f);
      unsigned long long key =
          ((unsigned long long)__float_as_uint(bv[t]) << 32) |
          (unsigned long long)(0xFFFFFFFFu - bj[t]);
      if (valid && key > best) best = key;
    }
#pragma unroll
    for (int d = 32; d >= 1; d >>= 1) {
      unsigned long long o = __shfl_xor(best, d);
      if (o > best) best = o;
    }
    unsigned wj = 0xFFFFFFFFu - (unsigned)(best & 0xFFFFFFFFull);
    if (lane == 0) t8i[row * 8 + pick] = wj;
#pragma unroll
    for (int t = 0; t < 8; ++t) if (bj[t] == wj) bv[t] = -1.0f;
  }
}

// ------- fp64-exact rerank -> exact top-4 — verbatim -------
__global__ __launch_bounds__(256) void rerank_k(const float* __restrict__ L,
                                                const float* __restrict__ U,
                                                const double* __restrict__ sqd,
                                                const unsigned* __restrict__ t8i,
                                                unsigned* __restrict__ t4i) {
  const int wave = threadIdx.x >> 6, lane = threadIdx.x & 63;
  const int row = blockIdx.x * 4 + wave;
  const float* xi = xrow(L, U, row);
  float xr[16];
#pragma unroll
  for (int t = 0; t < 16; ++t) xr[t] = xi[t * 64 + lane];
  unsigned cj[8];
  double cw[8];
#pragma unroll
  for (int c = 0; c < 8; ++c) cj[c] = t8i[row * 8 + c];
  for (int c = 0; c < 8; ++c) {
    const float* xj = xrow(L, U, (int)cj[c]);
    double s = 0.0;
#pragma unroll
    for (int t = 0; t < 16; ++t) s += (double)xr[t] * xj[t * 64 + lane];
#pragma unroll
    for (int d = 32; d >= 1; d >>= 1) s += __shfl_xor(s, d);
    double dist = (sqd[row] + sqd[cj[c]] - 2.0 * s) * (1.0 / 1024.0);
    cw[c] = exp(-0.5 * dist);
  }
  if (lane == 0) {
#pragma unroll
    for (int pick = 0; pick < 4; ++pick) {
      int ms = -1;
      double mv = -1.0;
      unsigned mj = 0xFFFFFFFFu;
#pragma unroll
      for (int c = 0; c < 8; ++c) {
        bool better = (cw[c] > mv) || (cw[c] == mv && cj[c] < mj);
        if (cw[c] >= 0.0 && better) { mv = cw[c]; mj = cj[c]; ms = c; }
      }
      t4i[row * 4 + pick] = mj;
      cw[ms] = -2.0;
    }
  }
}

// ------- count kept edges per row — verbatim -------
__global__ __launch_bounds__(256) void cnt4_k(const unsigned* __restrict__ t4i,
                                              unsigned* __restrict__ nn) {
  const int wave = threadIdx.x >> 6, lane = threadIdx.x & 63;
  const int i = blockIdx.x * 4 + wave;
  const uint4 mine = ((const uint4*)t4i)[i];
  unsigned base = 0;
  for (int j0 = 0; j0 < N_ALL; j0 += 64) {
    int j = j0 + lane;
    uint4 tj = ((const uint4*)t4i)[j];
    bool keep = (mine.x == (unsigned)j) | (mine.y == (unsigned)j) |
                (mine.z == (unsigned)j) | (mine.w == (unsigned)j) |
                (tj.x == (unsigned)i) | (tj.y == (unsigned)i) |
                (tj.z == (unsigned)i) | (tj.w == (unsigned)i);
    keep = keep && (j != i);
    base += (unsigned)__popcll(__ballot(keep));
  }
  if (lane == 0) nn[i] = base;
}

// ------- exclusive scan of nn -> CSR rowPtr + label-layout probe — verbatim -------
__global__ __launch_bounds__(64) void scanP_k(const unsigned* __restrict__ nn,
                                              unsigned* __restrict__ rowPtr,
                                              const int* __restrict__ lab,
                                              int* __restrict__ labflag) {
  const int lane = threadIdx.x;
  const long long* l64 = (const long long*)lab;
  int bad = 0;
#pragma unroll
  for (int k = 0; k < 8; ++k) {
    long long v = l64[k * 64 + lane];
    if (v != 0 && v != 1) bad = 1;
  }
  unsigned long long bm = __ballot(bad);
  if (lane == 0) labflag[0] = (bm != 0ull) ? 0 : 1;
  unsigned running = 0;
  for (int j0 = 0; j0 < N_ALL; j0 += 64) {
    int v = (int)nn[j0 + lane];
    int incl = v;
#pragma unroll
    for (int d = 1; d < 64; d <<= 1) {
      int t = __shfl_up(incl, d);
      if (lane >= d) incl += t;
    }
    rowPtr[j0 + lane] = running + (unsigned)(incl - v);
    running += (unsigned)__shfl(incl, 63);
  }
  if (lane == 0) rowPtr[N_ALL] = running;
}

// ------- CSR index fill — verbatim -------
__global__ __launch_bounds__(256) void csrfill_k(const unsigned* __restrict__ t4i,
                                                 const unsigned* __restrict__ rowPtr,
                                                 Edge* __restrict__ edges,
                                                 unsigned* __restrict__ eRow) {
  const int wave = threadIdx.x >> 6, lane = threadIdx.x & 63;
  const int i = blockIdx.x * 4 + wave;
  const uint4 mine = ((const uint4*)t4i)[i];
  unsigned base = rowPtr[i];
  for (int j0 = 0; j0 < N_ALL; j0 += 64) {
    int j = j0 + lane;
    uint4 tj = ((const uint4*)t4i)[j];
    bool keep = (mine.x == (unsigned)j) | (mine.y == (unsigned)j) |
                (mine.z == (unsigned)j) | (mine.w == (unsigned)j) |
                (tj.x == (unsigned)i) | (tj.y == (unsigned)i) |
                (tj.z == (unsigned)i) | (tj.w == (unsigned)i);
    keep = keep && (j != i);
    unsigned long long m = __ballot(keep);
    if (keep) {
      unsigned pos = base + (unsigned)__popcll(m & ((1ull << lane) - 1ull));
      edges[pos].j = (unsigned)j;
      edges[pos].w = 0.0f;
      eRow[pos] = (unsigned)i;
    }
    base += (unsigned)__popcll(m);
  }
}

// ------- exact edge values — verbatim -------
__global__ __launch_bounds__(256) void edgeval_k(const float* __restrict__ L,
                                                 const float* __restrict__ U,
                                                 const double* __restrict__ sqd,
                                                 const unsigned* __restrict__ rowPtr,
                                                 const unsigned* __restrict__ eRow,
                                                 Edge* __restrict__ edges) {
  const int wave = threadIdx.x >> 6, lane = threadIdx.x & 63;
  const unsigned e = blockIdx.x * 4 + wave;
  if (e >= rowPtr[N_ALL]) return;
  const unsigned i = eRow[e];
  const unsigned j = edges[e].j;
  const float* xi = xrow(L, U, (int)i);
  const float* xj = xrow(L, U, (int)j);
  double s = 0.0;
#pragma unroll
  for (int t = 0; t < 16; ++t)
    s += (double)xi[t * 64 + lane] * xj[t * 64 + lane];
#pragma unroll
  for (int d = 32; d >= 1; d >>= 1) s += __shfl_xor(s, d);
  if (lane == 0) {
    double dist = (sqd[i] + sqd[j] - 2.0 * s) * (1.0 / 1024.0);
    edges[e].w = (float)exp(-0.5 * dist);
  }
}

// ------- degrees from exact edge values — verbatim -------
__global__ __launch_bounds__(256) void degE_k(const unsigned* __restrict__ rowPtr,
                                              const Edge* __restrict__ edges,
                                              float* __restrict__ Dis) {
  const int wave = threadIdx.x >> 6, lane = threadIdx.x & 63;
  const int i = blockIdx.x * 4 + wave;
  const unsigned b0 = rowPtr[i], b1 = rowPtr[i + 1];
  double ds = 0.0;
  for (unsigned e = b0 + lane; e < b1; e += 64) ds += (double)edges[e].w;
#pragma unroll
  for (int d = 32; d >= 1; d >>= 1) ds += __shfl_xor(ds, d);
  if (lane == 0) Dis[i] = (float)sqrt(1.0 / (ds + EPS_D));
}

// ------- scale edges -> packed padded chunk stream with flush classes -------
// epk[e] = {(row<<16) | FLUSH(0x8000) | ATOMIC(0x4000) | j, w_scaled}.
// FLUSH: last edge of this row-segment within its 32-edge chunk.
// ATOMIC: the row's CSR span crosses this chunk's boundary -> combine via
// atomicAdd; otherwise the segment IS the whole row sum -> plain store.
// Interior rows (~80%) take the store path: no atomics, no RMW.
// Pads e in [E, EDGECAP): {0, 0.0f} -> accumulate 0, never flush.
__global__ __launch_bounds__(256) void scaleE_k(const unsigned* __restrict__ rowPtr,
                                                const unsigned* __restrict__ eRow,
                                                const float* __restrict__ Dis,
                                                const Edge* __restrict__ edges,
                                                uint2* __restrict__ epk) {
  const unsigned e = blockIdx.x * 256 + threadIdx.x;
  const unsigned E = rowPtr[N_ALL];
  if (e >= E) {
    if (e < EDGECAP) epk[e] = make_uint2(0u, 0u);
    return;
  }
  Edge ed = edges[e];
  const unsigned i = eRow[e];
  const float w = ed.w * Dis[i] * Dis[ed.j];
  const unsigned flush =
      ((e == E - 1) || (eRow[e + 1] != i) || ((e & 31u) == 31u)) ? 1u : 0u;
  unsigned bits = 0u;
  if (flush) {
    const unsigned cs = e & ~31u;
    const unsigned partial = (rowPtr[i] < cs) || (rowPtr[i + 1] > cs + 32u);
    bits = 0x8000u | (partial ? 0x4000u : 0u);
  }
  epk[e] = make_uint2((i << 16) | bits | ed.j, __float_as_uint(w));
}

// one packed edge: meta m, weight bits wb
#define EDGE1(m, wb)                                                     \
  do {                                                                   \
    const float w_ = __uint_as_float(wb);                                \
    const float2 dj_ = dsh[(m) & 0xFFFu];                                \
    sx += w_ * dj_.x;                                                    \
    sy += w_ * dj_.y;                                                    \
    if ((m) & 0x8000u) {                                                 \
      const unsigned row_ = (m) >> 16;                                   \
      if ((m) & 0x4000u) {                                               \
        atomicAdd(&acc[row_].x, sx);                                     \
        atomicAdd(&acc[row_].y, sy);                                     \
      } else {                                                           \
        acc[row_] = make_float2(sx, sy);                                 \
      }                                                                  \
      sx = 0.0f;                                                         \
      sy = 0.0f;                                                         \
    }                                                                    \
  } while (0)
#define EDGE2(v) EDGE1(v.x, v.y); EDGE1(v.z, v.w)

// ------- persistent single-workgroup Chebyshev solver, v4 -------
// v3 post-mortem: 37K cy/iter with VALUBusy ~6% of the CU — the unrolled
// inner loop's per-edge divergent flush (branch + 2 LDS atomicAdds) both
// serialized exec-mask work and blocked the compiler from hoisting the 32
// L2 edge loads, exposing ~250 cy L2 latency per edge. v4: (a) ~80% of
// flushes are whole-row segments (CSR span interior to one 32-chunk) ->
// plain ds_write, atomic only for chunk-spanning rows (ATOMIC bit from
// scaleE_k); (b) edge stream hand-pipelined as named uint4 ping-pong
// groups (8 live uint4 = 32 VGPR, all static indexing) so L2 loads batch
// and overlap gather+FMA. Phase B (row-owned update, acc re-zero) as v3.
__global__ __launch_bounds__(1024, 4) void chebsolve_k(
    const uint2* __restrict__ epk,
    const int* __restrict__ lab,
    const int* __restrict__ labflag,
    float2* __restrict__ out) {
  __shared__ float2 dsh[N_ALL];   // 32 KB: d vector
  __shared__ float2 acc[N_ALL];   // 32 KB: per-row gather results
  const int t = threadIdx.x;

  float2 xv[4], rv[4], dreg[4];
  const int isI64 = labflag[0];

#pragma unroll
  for (int q = 0; q < 4; ++q) {
    const int row = t + q * 1024;
    float2 b = make_float2(0.0f, 0.0f);
    if (q == 0) {  // rows < N_LAB are exactly q==0
      int c = isI64 ? lab[2 * row] : lab[row];
      b.x = (c == 0) ? 1.0f : 0.0f;
      b.y = (c == 1) ? 1.0f : 0.0f;
    }
    xv[q] = make_float2(0.0f, 0.0f);
    rv[q] = b;
    dreg[q] = b;
    dsh[row] = b;
    acc[row] = make_float2(0.0f, 0.0f);
  }
  __syncthreads();

  const double theta = 1.0, delta = 0.992;
  const double sigma1 = theta / delta;
  double rho = delta / theta;
  const uint4* ep4 = ((const uint4*)epk) + (size_t)t * 16;  // 16 uint4 = 32 edges

  for (int it = 0; it < NIT_CH; ++it) {
    const double rho_new = 1.0 / (2.0 * sigma1 - rho);
    const float c1 = (float)(rho_new * rho);
    const float c2 = (float)(2.0 * rho_new / delta);
    rho = rho_new;
    const bool last = (it == NIT_CH - 1);

    // ---- phase A: edge-parallel gather, pipelined loads, mostly-store flush
    float sx = 0.0f, sy = 0.0f;
    uint4 a0 = ep4[0], a1 = ep4[1], a2 = ep4[2], a3 = ep4[3];
    uint4 b0 = ep4[4], b1 = ep4[5], b2 = ep4[6], b3 = ep4[7];
    EDGE2(a0); EDGE2(a1); EDGE2(a2); EDGE2(a3);
    a0 = ep4[8]; a1 = ep4[9]; a2 = ep4[10]; a3 = ep4[11];
    EDGE2(b0); EDGE2(b1); EDGE2(b2); EDGE2(b3);
    b0 = ep4[12]; b1 = ep4[13]; b2 = ep4[14]; b3 = ep4[15];
    EDGE2(a0); EDGE2(a1); EDGE2(a2); EDGE2(a3);
    EDGE2(b0); EDGE2(b1); EDGE2(b2); EDGE2(b3);
    __syncthreads();  // all stores+atomics visible before row-owned update

    // ---- phase B: row-owned update; re-zero acc for the next iteration ----
#pragma unroll
    for (int q = 0; q < 4; ++q) {
      const int row = t + q * 1024;
      const float2 a = acc[row];
      acc[row] = make_float2(0.0f, 0.0f);
      const float2 di = dreg[q];
      xv[q].x += di.x;
      xv[q].y += di.y;
      rv[q].x += ALPHA_ * a.x - di.x;
      rv[q].y += ALPHA_ * a.y - di.y;
      if (!last) {
        float2 dn;
        dn.x = c1 * di.x + c2 * rv[q].x;
        dn.y = c1 * di.y + c2 * rv[q].y;
        dreg[q] = dn;
        dsh[row] = dn;
      }
    }
    __syncthreads();  // d + zeroed acc visible before next gather
  }

#pragma unroll
  for (int q = 1; q < 4; ++q) {
    const int row = t + q * 1024;
    out[row - N_LAB] = xv[q];
  }
}

// ---------------- launch ----------------
extern "C" void kernel_launch(void* const* d_in, const int* in_sizes, int n_in,
                              void* d_out, int out_size, void* d_ws, size_t ws_size,
                              hipStream_t stream) {
  int iL = 0, iT = 1, iU = 2;
  for (int i = 0; i < n_in; ++i) {
    if (in_sizes[i] == N_LAB * DIMF) iL = i;
    else if (in_sizes[i] == (N_ALL - N_LAB) * DIMF) iU = i;
    else iT = i;
  }
  const float* L = (const float*)d_in[iL];
  const int* lab = (const int*)d_in[iT];
  const float* U = (const float*)d_in[iU];
  float2* out = (float2*)d_out;

  char* w = (char*)d_ws;
  size_t off = 0;
  auto alloc = [&](size_t bytes) {
    void* p = (void*)(w + off);
    off += (bytes + 255) & ~(size_t)255;
    return p;
  };
  _Float16* Wh = (_Float16*)alloc((size_t)N_ALL * N_ALL * 2);     // 32 MB proxy
  unsigned short* Xbf = (unsigned short*)alloc((size_t)N_ALL * DIMF * 2);  // 8 MB
  float* sq = (float*)alloc(N_ALL * 4);
  double* sqd = (double*)alloc(N_ALL * 8);
  unsigned* t8i = (unsigned*)alloc(N_ALL * 8 * 4);
  unsigned* t4i = (unsigned*)alloc(N_ALL * 4 * 4);
  float* Dis = (float*)alloc(N_ALL * 4);
  unsigned* nn = (unsigned*)alloc(N_ALL * 4);
  unsigned* rowPtr = (unsigned*)alloc((N_ALL + 1) * 4);
  int* labflag = (int*)alloc(256);
  Edge* edges = (Edge*)alloc((size_t)EDGECAP * sizeof(Edge));     // 256 KB
  unsigned* eRow = (unsigned*)alloc((size_t)EDGECAP * 4);         // 128 KB
  uint2* epk = (uint2*)alloc((size_t)EDGECAP * 8);                // 256 KB packed
  if (off > ws_size) return;

  prep_k<<<N_ALL, 256, 0, stream>>>(L, U, Xbf, sq, sqd);
  gemm_w<<<dim3(32, 32), 256, 0, stream>>>(Xbf, sq, Wh);
  top8_k<<<N_ALL / 4, 256, 0, stream>>>(Wh, t8i);
  rerank_k<<<N_ALL / 4, 256, 0, stream>>>(L, U, sqd, t8i, t4i);
  cnt4_k<<<N_ALL / 4, 256, 0, stream>>>(t4i, nn);
  scanP_k<<<1, 64, 0, stream>>>(nn, rowPtr, lab, labflag);
  csrfill_k<<<N_ALL / 4, 256, 0, stream>>>(t4i, rowPtr, edges, eRow);
  edgeval_k<<<EDGECAP / 4, 256, 0, stream>>>(L, U, sqd, rowPtr, eRow, edges);
  degE_k<<<N_ALL / 4, 256, 0, stream>>>(rowPtr, edges, Dis);
  scaleE_k<<<EDGECAP / 256, 256, 0, stream>>>(rowPtr, eRow, Dis, edges, epk);
  chebsolve_k<<<1, 1024, 0, stream>>>(epk, lab, labflag, out);
}